// Round 1
// baseline (746.425 us; speedup 1.0000x reference)
//
#include <hip/hip_runtime.h>
#include <math.h>

// Problem constants
#define NB 32
#define CI 64
#define CO 64
#define CA 16
#define NK 4
#define HH 128
#define WW 128
#define EPSBN 1e-5f

// Workspace layout (in floats)
#define WS_POOLED 0            // 32*64  = 2048
#define WS_CHA    2048         // 32*64  = 2048
#define WS_FA     4096         // 32*64  = 2048
#define WS_KA     6144         // 32*4   = 128
#define WS_SP     6272         // 32*9   = 288
#define WS_W2     8192         // 32*64*64*9 = 1179648

// ---------------------------------------------------------------------------
// 1) Global average pool: one block per (b,c) plane of 128*128 floats
// ---------------------------------------------------------------------------
__global__ void pool_kernel(const float* __restrict__ x, float* __restrict__ pooled) {
    const int plane = blockIdx.x;               // b*64 + c, 2048 planes
    const float4* p = (const float4*)(x + (size_t)plane * (HH * WW));
    float s = 0.f;
    for (int j = threadIdx.x; j < (HH * WW) / 4; j += 256) {
        float4 v = p[j];
        s += v.x + v.y + v.z + v.w;
    }
    // wave reduce (64 lanes)
    #pragma unroll
    for (int off = 32; off > 0; off >>= 1) s += __shfl_down(s, off);
    __shared__ float red[4];
    if ((threadIdx.x & 63) == 0) red[threadIdx.x >> 6] = s;
    __syncthreads();
    if (threadIdx.x == 0)
        pooled[plane] = (red[0] + red[1] + red[2] + red[3]) * (1.f / (HH * WW));
}

// ---------------------------------------------------------------------------
// 2) Attention trunk + 4 heads. Tiny: 1 block, thread t = sample b.
// ---------------------------------------------------------------------------
__global__ void attn_kernel(const float* __restrict__ pooled,
                            const float* __restrict__ prep_w,
                            const float* __restrict__ bn_g, const float* __restrict__ bn_b,
                            const float* __restrict__ bn_m, const float* __restrict__ bn_v,
                            const float* __restrict__ fc_sp_w, const float* __restrict__ fc_sp_b,
                            const float* __restrict__ fc_ch_w, const float* __restrict__ fc_ch_b,
                            const float* __restrict__ fc_f_w,  const float* __restrict__ fc_f_b,
                            const float* __restrict__ fc_k_w,  const float* __restrict__ fc_k_b,
                            float* __restrict__ sp, float* __restrict__ cha,
                            float* __restrict__ fa, float* __restrict__ ka) {
    const int b = threadIdx.x;
    if (b >= NB) return;
    float att[CA];
    #pragma unroll
    for (int a = 0; a < CA; ++a) {
        float s = 0.f;
        for (int c = 0; c < CI; ++c) s += pooled[b * CI + c] * prep_w[a * CI + c];
        s = (s - bn_m[a]) * rsqrtf(bn_v[a] + EPSBN) * bn_g[a] + bn_b[a];
        att[a] = fmaxf(s, 0.f);
    }
    for (int j = 0; j < 9; ++j) {
        float s = fc_sp_b[j];
        #pragma unroll
        for (int a = 0; a < CA; ++a) s += att[a] * fc_sp_w[j * CA + a];
        sp[b * 9 + j] = 1.f / (1.f + expf(-s));
    }
    for (int j = 0; j < CI; ++j) {
        float s = fc_ch_b[j];
        #pragma unroll
        for (int a = 0; a < CA; ++a) s += att[a] * fc_ch_w[j * CA + a];
        cha[b * CI + j] = 1.f / (1.f + expf(-s));
    }
    for (int j = 0; j < CO; ++j) {
        float s = fc_f_b[j];
        #pragma unroll
        for (int a = 0; a < CA; ++a) s += att[a] * fc_f_w[j * CA + a];
        fa[b * CO + j] = 1.f / (1.f + expf(-s));
    }
    float kv[NK], m = -1e30f;
    #pragma unroll
    for (int j = 0; j < NK; ++j) {
        float s = fc_k_b[j];
        #pragma unroll
        for (int a = 0; a < CA; ++a) s += att[a] * fc_k_w[j * CA + a];
        kv[j] = s;
        m = fmaxf(m, s);
    }
    float den = 0.f;
    #pragma unroll
    for (int j = 0; j < NK; ++j) { kv[j] = expf(kv[j] - m); den += kv[j]; }
    #pragma unroll
    for (int j = 0; j < NK; ++j) ka[b * NK + j] = kv[j] / den;
}

// ---------------------------------------------------------------------------
// 3) Synthesize folded per-sample weights:
//    w2[b,o,i,uv] = fa[b,o]*cha[b,i]*sp[b,uv]*sum_k ka[b,k]*kernels[k,o,i,uv]
// ---------------------------------------------------------------------------
__global__ void w2_kernel(const float* __restrict__ kernels,
                          const float* __restrict__ sp, const float* __restrict__ cha,
                          const float* __restrict__ fa, const float* __restrict__ ka,
                          float* __restrict__ w2) {
    const int idx = blockIdx.x * 256 + threadIdx.x;    // 32*64*64*9 = 1179648 total
    if (idx >= NB * CO * CI * 9) return;
    const int uv = idx % 9;
    const int i  = (idx / 9) % CI;
    const int o  = (idx / (9 * CI)) % CO;
    const int b  = idx / (9 * CI * CO);
    float s = 0.f;
    #pragma unroll
    for (int k = 0; k < NK; ++k)
        s += ka[b * NK + k] * kernels[((k * CO + o) * CI + i) * 9 + uv];
    w2[idx] = s * sp[b * 9 + uv] * cha[b * CI + i] * fa[b * CO + o];
}

// ---------------------------------------------------------------------------
// 4) Per-sample 3x3 conv, pad 1.
//    Block: tile = 64 o x 8 rows x 16 cols. 256 threads: o = tid>>3 (handles o
//    and o+32), q = tid&7 (row). ci staged in chunks of 16.
//    LDS: xs[16 ci][10 rows][20 cols(pad)], ws[144 iuv][65(o pad)]
// ---------------------------------------------------------------------------
#define CICHUNK 16
__global__ __launch_bounds__(256) void conv_kernel(const float* __restrict__ x,
                                                   const float* __restrict__ w2,
                                                   float* __restrict__ out) {
    __shared__ float xs[CICHUNK * 10 * 20];
    __shared__ float ws[144 * 65];

    const int tid = threadIdx.x;
    const int o   = tid >> 3;        // 0..31, handles o and o+32
    const int q   = tid & 7;         // row within tile
    const int w0  = blockIdx.x * 16;
    const int h0  = blockIdx.y * 8;
    const int b   = blockIdx.z;

    float acc0[16], acc1[16];
    #pragma unroll
    for (int c = 0; c < 16; ++c) { acc0[c] = 0.f; acc1[c] = 0.f; }

    const float* w2b = w2 + (size_t)b * (CO * CI * 9);

    for (int ci0 = 0; ci0 < CI; ci0 += CICHUNK) {
        __syncthreads();
        // stage x tile: 16 ci x 10 rows x 18 cols (zero-padded at borders)
        for (int lidx = tid; lidx < CICHUNK * 10 * 18; lidx += 256) {
            const int i   = lidx / 180;
            const int rem = lidx - i * 180;
            const int r   = rem / 18;
            const int c   = rem - r * 18;
            const int hh  = h0 - 1 + r;
            const int cc  = w0 - 1 + c;
            float val = 0.f;
            if ((unsigned)hh < (unsigned)HH && (unsigned)cc < (unsigned)WW)
                val = x[((size_t)(b * CI + ci0 + i) * HH + hh) * WW + cc];
            xs[(i * 10 + r) * 20 + c] = val;
        }
        // stage weights: w2[b, oo, ci0+i, uv] -> ws[(i*9+uv)*65 + oo]
        for (int g = tid; g < CO * CICHUNK * 9; g += 256) {
            const int oo  = g / (CICHUNK * 9);
            const int iuv = g - oo * (CICHUNK * 9);
            ws[iuv * 65 + oo] = w2b[oo * (CI * 9) + ci0 * 9 + iuv];
        }
        __syncthreads();

        #pragma unroll
        for (int i = 0; i < CICHUNK; ++i) {
            float wv0[9], wv1[9];
            #pragma unroll
            for (int t = 0; t < 9; ++t) {
                wv0[t] = ws[(i * 9 + t) * 65 + o];
                wv1[t] = ws[(i * 9 + t) * 65 + o + 32];
            }
            #pragma unroll
            for (int u = 0; u < 3; ++u) {
                const float4* xp = (const float4*)&xs[(i * 10 + q + u) * 20];
                float xf[20];
                #pragma unroll
                for (int t = 0; t < 5; ++t) {
                    float4 v = xp[t];
                    xf[4 * t + 0] = v.x; xf[4 * t + 1] = v.y;
                    xf[4 * t + 2] = v.z; xf[4 * t + 3] = v.w;
                }
                #pragma unroll
                for (int v = 0; v < 3; ++v) {
                    const float wa = wv0[u * 3 + v];
                    const float wb = wv1[u * 3 + v];
                    #pragma unroll
                    for (int c = 0; c < 16; ++c) {
                        acc0[c] = fmaf(wa, xf[c + v], acc0[c]);
                        acc1[c] = fmaf(wb, xf[c + v], acc1[c]);
                    }
                }
            }
        }
    }

    float* op0 = out + ((size_t)(b * CO + o) * HH + h0 + q) * WW + w0;
    float* op1 = out + ((size_t)(b * CO + o + 32) * HH + h0 + q) * WW + w0;
    #pragma unroll
    for (int t = 0; t < 4; ++t) {
        ((float4*)op0)[t] = make_float4(acc0[4*t], acc0[4*t+1], acc0[4*t+2], acc0[4*t+3]);
        ((float4*)op1)[t] = make_float4(acc1[4*t], acc1[4*t+1], acc1[4*t+2], acc1[4*t+3]);
    }
}

// ---------------------------------------------------------------------------
extern "C" void kernel_launch(void* const* d_in, const int* in_sizes, int n_in,
                              void* d_out, int out_size, void* d_ws, size_t ws_size,
                              hipStream_t stream) {
    const float* x        = (const float*)d_in[0];
    const float* prep_w   = (const float*)d_in[1];
    const float* bn_g     = (const float*)d_in[2];
    const float* bn_b     = (const float*)d_in[3];
    const float* bn_m     = (const float*)d_in[4];
    const float* bn_v     = (const float*)d_in[5];
    const float* fc_sp_w  = (const float*)d_in[6];
    const float* fc_sp_b  = (const float*)d_in[7];
    const float* fc_ch_w  = (const float*)d_in[8];
    const float* fc_ch_b  = (const float*)d_in[9];
    const float* fc_f_w   = (const float*)d_in[10];
    const float* fc_f_b   = (const float*)d_in[11];
    const float* fc_k_w   = (const float*)d_in[12];
    const float* fc_k_b   = (const float*)d_in[13];
    const float* kernels  = (const float*)d_in[14];
    float* out = (float*)d_out;
    float* ws  = (float*)d_ws;

    float* pooled = ws + WS_POOLED;
    float* cha    = ws + WS_CHA;
    float* fa     = ws + WS_FA;
    float* ka     = ws + WS_KA;
    float* sp     = ws + WS_SP;
    float* w2     = ws + WS_W2;

    pool_kernel<<<NB * CI, 256, 0, stream>>>(x, pooled);
    attn_kernel<<<1, 64, 0, stream>>>(pooled, prep_w, bn_g, bn_b, bn_m, bn_v,
                                      fc_sp_w, fc_sp_b, fc_ch_w, fc_ch_b,
                                      fc_f_w, fc_f_b, fc_k_w, fc_k_b,
                                      sp, cha, fa, ka);
    {
        const int total = NB * CO * CI * 9;
        w2_kernel<<<(total + 255) / 256, 256, 0, stream>>>(kernels, sp, cha, fa, ka, w2);
    }
    {
        dim3 grid(WW / 16, HH / 8, NB);
        conv_kernel<<<grid, 256, 0, stream>>>(x, w2, out);
    }
}

// Round 2
// 328.262 us; speedup vs baseline: 2.2739x; 2.2739x over previous
//
#include <hip/hip_runtime.h>
#include <math.h>

// Problem constants
#define NB 32
#define CI 64
#define CO 64
#define CA 16
#define NK 4
#define HH 128
#define WW 128
#define EPSBN 1e-5f

typedef __bf16 bf16x8 __attribute__((ext_vector_type(8)));
typedef float f32x16 __attribute__((ext_vector_type(16)));

__device__ inline unsigned short f2bf(float f) {
    union { float f; unsigned u; } c; c.f = f;
    return (unsigned short)((c.u + 0x7fffu + ((c.u >> 16) & 1u)) >> 16);
}

// Workspace layout (float offsets)
#define WS_POOLED 0            // 2048
#define WS_CHA    2048         // 2048
#define WS_FA     4096         // 2048
#define WS_KA     6144         // 128
#define WS_SP     6272         // 288
#define WS_W2T    8192         // 1179648 ushorts (2.36 MB) as bf16 [b][tap][o][i]

// ---------------------------------------------------------------------------
// 1) Global average pool: one block per (b,c) plane
// ---------------------------------------------------------------------------
__global__ void pool_kernel(const float* __restrict__ x, float* __restrict__ pooled) {
    const int plane = blockIdx.x;
    const float4* p = (const float4*)(x + (size_t)plane * (HH * WW));
    float s = 0.f;
    for (int j = threadIdx.x; j < (HH * WW) / 4; j += 256) {
        float4 v = p[j];
        s += v.x + v.y + v.z + v.w;
    }
    #pragma unroll
    for (int off = 32; off > 0; off >>= 1) s += __shfl_down(s, off);
    __shared__ float red[4];
    if ((threadIdx.x & 63) == 0) red[threadIdx.x >> 6] = s;
    __syncthreads();
    if (threadIdx.x == 0)
        pooled[plane] = (red[0] + red[1] + red[2] + red[3]) * (1.f / (HH * WW));
}

// ---------------------------------------------------------------------------
// 2) Attention trunk + 4 heads (tiny)
// ---------------------------------------------------------------------------
__global__ void attn_kernel(const float* __restrict__ pooled,
                            const float* __restrict__ prep_w,
                            const float* __restrict__ bn_g, const float* __restrict__ bn_b,
                            const float* __restrict__ bn_m, const float* __restrict__ bn_v,
                            const float* __restrict__ fc_sp_w, const float* __restrict__ fc_sp_b,
                            const float* __restrict__ fc_ch_w, const float* __restrict__ fc_ch_b,
                            const float* __restrict__ fc_f_w,  const float* __restrict__ fc_f_b,
                            const float* __restrict__ fc_k_w,  const float* __restrict__ fc_k_b,
                            float* __restrict__ sp, float* __restrict__ cha,
                            float* __restrict__ fa, float* __restrict__ ka) {
    const int b = threadIdx.x;
    if (b >= NB) return;
    float att[CA];
    #pragma unroll
    for (int a = 0; a < CA; ++a) {
        float s = 0.f;
        for (int c = 0; c < CI; ++c) s += pooled[b * CI + c] * prep_w[a * CI + c];
        s = (s - bn_m[a]) * rsqrtf(bn_v[a] + EPSBN) * bn_g[a] + bn_b[a];
        att[a] = fmaxf(s, 0.f);
    }
    for (int j = 0; j < 9; ++j) {
        float s = fc_sp_b[j];
        #pragma unroll
        for (int a = 0; a < CA; ++a) s += att[a] * fc_sp_w[j * CA + a];
        sp[b * 9 + j] = 1.f / (1.f + expf(-s));
    }
    for (int j = 0; j < CI; ++j) {
        float s = fc_ch_b[j];
        #pragma unroll
        for (int a = 0; a < CA; ++a) s += att[a] * fc_ch_w[j * CA + a];
        cha[b * CI + j] = 1.f / (1.f + expf(-s));
    }
    for (int j = 0; j < CO; ++j) {
        float s = fc_f_b[j];
        #pragma unroll
        for (int a = 0; a < CA; ++a) s += att[a] * fc_f_w[j * CA + a];
        fa[b * CO + j] = 1.f / (1.f + expf(-s));
    }
    float kv[NK], m = -1e30f;
    #pragma unroll
    for (int j = 0; j < NK; ++j) {
        float s = fc_k_b[j];
        #pragma unroll
        for (int a = 0; a < CA; ++a) s += att[a] * fc_k_w[j * CA + a];
        kv[j] = s;
        m = fmaxf(m, s);
    }
    float den = 0.f;
    #pragma unroll
    for (int j = 0; j < NK; ++j) { kv[j] = expf(kv[j] - m); den += kv[j]; }
    #pragma unroll
    for (int j = 0; j < NK; ++j) ka[b * NK + j] = kv[j] / den;
}

// ---------------------------------------------------------------------------
// 3) Folded weights, transposed for MFMA A-fragments:
//    w2t[b][tap][o][i] (bf16) = fa*cha*sp*sum_k ka*kernels
// ---------------------------------------------------------------------------
__global__ void w2t_kernel(const float* __restrict__ kernels,
                           const float* __restrict__ sp, const float* __restrict__ cha,
                           const float* __restrict__ fa, const float* __restrict__ ka,
                           unsigned short* __restrict__ w2t) {
    const int idx = blockIdx.x * 256 + threadIdx.x;    // 32*9*64*64 = 1179648 exact
    const int i   = idx & 63;
    const int o   = (idx >> 6) & 63;
    const int tap = (idx >> 12) % 9;
    const int b   = idx / (9 * 4096);
    float s = 0.f;
    #pragma unroll
    for (int k = 0; k < NK; ++k)
        s += ka[b * NK + k] * kernels[((k * CO + o) * CI + i) * 9 + tap];
    w2t[idx] = f2bf(s * sp[b * 9 + tap] * cha[b * CI + i] * fa[b * CO + o]);
}

// ---------------------------------------------------------------------------
// 4) Tap-split implicit GEMM conv via mfma_f32_32x32x16_bf16.
//    Block: 64 co x 8 rows x 32 cols. 4 waves: (co_half, row_half).
//    LDS: x tile bf16, ci-inner, XOR-swizzled: byte = (r*34+c)*128 + (2k ^ ((c&7)<<4))
// ---------------------------------------------------------------------------
__global__ __launch_bounds__(256, 3) void conv_mfma(const float* __restrict__ x,
                                                    const unsigned short* __restrict__ w2t,
                                                    float* __restrict__ out) {
    __shared__ __align__(16) unsigned char xsb[10 * 34 * 128];   // 43520 B

    const int tid    = threadIdx.x;
    const int lane   = tid & 63;
    const int wave   = tid >> 6;
    const int n      = lane & 31;     // pixel col within tile / A row (o)
    const int kh     = lane >> 5;     // k-half
    const int cohalf = wave & 1;
    const int rhalf  = wave >> 1;
    const int w0 = blockIdx.x * 32;
    const int h0 = blockIdx.y * 8;
    const int b  = blockIdx.z;

    // ---- stage x tile: 32 ci-pairs x 10 rows, each unit packs 2 ci per u32 write
    for (int u = tid; u < 320; u += 256) {
        const int p = u & 31;
        const int r = u >> 5;
        const int hh = h0 - 1 + r;
        const bool hok = (unsigned)hh < (unsigned)HH;
        const float* s0 = x + (((size_t)(b * CI + 2 * p) * HH + hh) * WW);
        const float* s1 = s0 + HH * WW;
        unsigned char* dst = xsb + r * 34 * 128;
        #pragma unroll
        for (int j = 0; j < 10; ++j) {
            const int cg = w0 - 4 + 4 * j;
            float4 a = make_float4(0.f, 0.f, 0.f, 0.f);
            float4 bb = make_float4(0.f, 0.f, 0.f, 0.f);
            if (hok && (unsigned)cg < (unsigned)WW) {
                a  = *(const float4*)(s0 + cg);
                bb = *(const float4*)(s1 + cg);
            }
            const float av[4] = {a.x, a.y, a.z, a.w};
            const float bv[4] = {bb.x, bb.y, bb.z, bb.w};
            #pragma unroll
            for (int e = 0; e < 4; ++e) {
                const int c = 4 * j + e - 3;
                if ((unsigned)c < 34u) {
                    const unsigned v = (unsigned)f2bf(av[e]) | ((unsigned)f2bf(bv[e]) << 16);
                    *(unsigned*)(dst + c * 128 + ((4 * p) ^ ((c & 7) << 4))) = v;
                }
            }
        }
    }
    __syncthreads();

    // ---- compute: 9 taps x 4 ksteps, B row-fragments shared across (u,t)
    const unsigned short* w2b = w2t + (size_t)b * 9 * 4096
                              + (size_t)(cohalf * 32 + n) * 64 + kh * 8;

    f32x16 acc[4];
    #pragma unroll
    for (int t = 0; t < 4; ++t)
        #pragma unroll
        for (int q = 0; q < 16; ++q) acc[t][q] = 0.f;

    #pragma unroll 1
    for (int v = 0; v < 3; ++v) {
        const int c = n + v;
        const int swz = (c & 7) << 4;
        const unsigned char* rowp = xsb + (rhalf * 4 * 34 + c) * 128;
        #pragma unroll 1
        for (int ks = 0; ks < 4; ++ks) {
            const int koff = ks * 32 + kh * 16;
            bf16x8 Bf[6];
            #pragma unroll
            for (int rr = 0; rr < 6; ++rr)
                Bf[rr] = *(const bf16x8*)(rowp + rr * (34 * 128) + (koff ^ swz));
            #pragma unroll
            for (int u = 0; u < 3; ++u) {
                const bf16x8 Af = *(const bf16x8*)(w2b + (u * 3 + v) * 4096 + ks * 16);
                #pragma unroll
                for (int t = 0; t < 4; ++t)
                    acc[t] = __builtin_amdgcn_mfma_f32_32x32x16_bf16(Af, Bf[t + u], acc[t], 0, 0, 0);
            }
        }
    }

    // ---- epilogue: C row = (reg&3) + 8*(reg>>2) + 4*kh, col = n
    const int hbase = h0 + rhalf * 4;
    float* op = out + (size_t)(b * CO + cohalf * 32) * (HH * WW) + w0 + n;
    #pragma unroll
    for (int t = 0; t < 4; ++t) {
        const int h = hbase + t;
        #pragma unroll
        for (int reg = 0; reg < 16; ++reg) {
            const int m = (reg & 3) + 8 * (reg >> 2) + 4 * kh;
            op[(size_t)m * (HH * WW) + h * WW] = acc[t][reg];
        }
    }
}

// ---------------------------------------------------------------------------
extern "C" void kernel_launch(void* const* d_in, const int* in_sizes, int n_in,
                              void* d_out, int out_size, void* d_ws, size_t ws_size,
                              hipStream_t stream) {
    const float* x        = (const float*)d_in[0];
    const float* prep_w   = (const float*)d_in[1];
    const float* bn_g     = (const float*)d_in[2];
    const float* bn_b     = (const float*)d_in[3];
    const float* bn_m     = (const float*)d_in[4];
    const float* bn_v     = (const float*)d_in[5];
    const float* fc_sp_w  = (const float*)d_in[6];
    const float* fc_sp_b  = (const float*)d_in[7];
    const float* fc_ch_w  = (const float*)d_in[8];
    const float* fc_ch_b  = (const float*)d_in[9];
    const float* fc_f_w   = (const float*)d_in[10];
    const float* fc_f_b   = (const float*)d_in[11];
    const float* fc_k_w   = (const float*)d_in[12];
    const float* fc_k_b   = (const float*)d_in[13];
    const float* kernels  = (const float*)d_in[14];
    float* out = (float*)d_out;
    float* ws  = (float*)d_ws;

    float* pooled = ws + WS_POOLED;
    float* cha    = ws + WS_CHA;
    float* fa     = ws + WS_FA;
    float* ka     = ws + WS_KA;
    float* sp     = ws + WS_SP;
    unsigned short* w2t = (unsigned short*)(ws + WS_W2T);

    pool_kernel<<<NB * CI, 256, 0, stream>>>(x, pooled);
    attn_kernel<<<1, 64, 0, stream>>>(pooled, prep_w, bn_g, bn_b, bn_m, bn_v,
                                      fc_sp_w, fc_sp_b, fc_ch_w, fc_ch_b,
                                      fc_f_w, fc_f_b, fc_k_w, fc_k_b,
                                      sp, cha, fa, ka);
    w2t_kernel<<<(NB * 9 * CO * CI) / 256, 256, 0, stream>>>(kernels, sp, cha, fa, ka, w2t);
    {
        dim3 grid(WW / 32, HH / 8, NB);
        conv_mfma<<<grid, 256, 0, stream>>>(x, w2t, out);
    }
}

// Round 3
// 176.896 us; speedup vs baseline: 4.2196x; 1.8557x over previous
//
#include <hip/hip_runtime.h>
#include <math.h>

// Problem constants
#define NB 32
#define CI 64
#define CO 64
#define CA 16
#define NK 4
#define HH 128
#define WW 128
#define EPSBN 1e-5f

typedef __bf16 bf16x8 __attribute__((ext_vector_type(8)));
typedef float f32x16 __attribute__((ext_vector_type(16)));

__device__ inline unsigned short f2bf(float f) {
    union { float f; unsigned u; } c; c.f = f;
    return (unsigned short)((c.u + 0x7fffu + ((c.u >> 16) & 1u)) >> 16);
}

// Workspace layout (float offsets)
#define WS_POOLED 0            // 2048
#define WS_CHA    2048         // 2048
#define WS_FA     4096         // 2048
#define WS_KA     6144         // 128
#define WS_SP     6272         // 288
#define WS_W2T    8192         // 1179648 ushorts as bf16 [b][tap][o][i]

// ---------------------------------------------------------------------------
// 1) Global average pool: one block per (b,c) plane
// ---------------------------------------------------------------------------
__global__ void pool_kernel(const float* __restrict__ x, float* __restrict__ pooled) {
    const int plane = blockIdx.x;
    const float4* p = (const float4*)(x + (size_t)plane * (HH * WW));
    float s = 0.f;
    for (int j = threadIdx.x; j < (HH * WW) / 4; j += 256) {
        float4 v = p[j];
        s += v.x + v.y + v.z + v.w;
    }
    #pragma unroll
    for (int off = 32; off > 0; off >>= 1) s += __shfl_down(s, off);
    __shared__ float red[4];
    if ((threadIdx.x & 63) == 0) red[threadIdx.x >> 6] = s;
    __syncthreads();
    if (threadIdx.x == 0)
        pooled[plane] = (red[0] + red[1] + red[2] + red[3]) * (1.f / (HH * WW));
}

// ---------------------------------------------------------------------------
// 2) Attention trunk + heads, parallel: 512 threads = (b, a) pairs
// ---------------------------------------------------------------------------
__global__ __launch_bounds__(512) void attn2_kernel(
    const float* __restrict__ pooled, const float* __restrict__ prep_w,
    const float* __restrict__ bn_g, const float* __restrict__ bn_b,
    const float* __restrict__ bn_m, const float* __restrict__ bn_v,
    const float* __restrict__ fc_sp_w, const float* __restrict__ fc_sp_b,
    const float* __restrict__ fc_ch_w, const float* __restrict__ fc_ch_b,
    const float* __restrict__ fc_f_w,  const float* __restrict__ fc_f_b,
    const float* __restrict__ fc_k_w,  const float* __restrict__ fc_k_b,
    float* __restrict__ sp, float* __restrict__ cha,
    float* __restrict__ fa, float* __restrict__ ka) {
    __shared__ float att_s[NB * CA];
    const int tid = threadIdx.x;
    const int b = tid >> 4, a = tid & 15;
    {
        const float4* pv = (const float4*)(pooled + b * CI);
        const float4* wv = (const float4*)(prep_w + a * CI);
        float s = 0.f;
        #pragma unroll
        for (int i = 0; i < 16; ++i) {
            float4 p = pv[i], w = wv[i];
            s += p.x * w.x + p.y * w.y + p.z * w.z + p.w * w.w;
        }
        s = (s - bn_m[a]) * rsqrtf(bn_v[a] + EPSBN) * bn_g[a] + bn_b[a];
        att_s[b * CA + a] = fmaxf(s, 0.f);
    }
    __syncthreads();
    float av[CA];
    #pragma unroll
    for (int i = 0; i < CA; ++i) av[i] = att_s[b * CA + i];

    const int j = a;
    // spatial head (9 outputs per b)
    if (j < 9) {
        float s = fc_sp_b[j];
        #pragma unroll
        for (int i = 0; i < CA; ++i) s += av[i] * fc_sp_w[j * CA + i];
        sp[b * 9 + j] = 1.f / (1.f + expf(-s));
    }
    // channel + filter heads (64 each): 4 outputs per (b,j)
    #pragma unroll
    for (int t = 0; t < 4; ++t) {
        const int c = j * 4 + t;
        float s1 = fc_ch_b[c], s2 = fc_f_b[c];
        #pragma unroll
        for (int i = 0; i < CA; ++i) {
            s1 += av[i] * fc_ch_w[c * CA + i];
            s2 += av[i] * fc_f_w[c * CA + i];
        }
        cha[b * CI + c] = 1.f / (1.f + expf(-s1));
        fa[b * CO + c]  = 1.f / (1.f + expf(-s2));
    }
    // kernel head softmax
    if (j == 0) {
        float kv[NK], m = -1e30f;
        #pragma unroll
        for (int k = 0; k < NK; ++k) {
            float s = fc_k_b[k];
            #pragma unroll
            for (int i = 0; i < CA; ++i) s += av[i] * fc_k_w[k * CA + i];
            kv[k] = s; m = fmaxf(m, s);
        }
        float den = 0.f;
        #pragma unroll
        for (int k = 0; k < NK; ++k) { kv[k] = expf(kv[k] - m); den += kv[k]; }
        #pragma unroll
        for (int k = 0; k < NK; ++k) ka[b * NK + k] = kv[k] / den;
    }
}

// ---------------------------------------------------------------------------
// 3) Folded weights, transposed for MFMA A-fragments: w2t[b][tap][o][i] bf16
// ---------------------------------------------------------------------------
__global__ void w2t_kernel(const float* __restrict__ kernels,
                           const float* __restrict__ sp, const float* __restrict__ cha,
                           const float* __restrict__ fa, const float* __restrict__ ka,
                           unsigned short* __restrict__ w2t) {
    const int idx = blockIdx.x * 256 + threadIdx.x;    // 32*9*64*64 = 1179648 exact
    const int i   = idx & 63;
    const int o   = (idx >> 6) & 63;
    const int tap = (idx >> 12) % 9;
    const int b   = idx / (9 * 4096);
    float s = 0.f;
    #pragma unroll
    for (int k = 0; k < NK; ++k)
        s += ka[b * NK + k] * kernels[((k * CO + o) * CI + i) * 9 + tap];
    w2t[idx] = f2bf(s * sp[b * 9 + tap] * cha[b * CI + i] * fa[b * CO + o]);
}

// ---------------------------------------------------------------------------
// 4) Implicit-GEMM conv, 64co x 8rows x 64cols per block, ci chunks of 16,
//    double-buffered LDS + T14 load/write split.
//    LDS per buffer: [10 r][66 c][16 ci] bf16, 32 B per (r,c) column,
//    1-bit XOR swizzle on the ci-halves: byte = (r*66+c)*32 + (off ^ ((c&1)<<4))
// ---------------------------------------------------------------------------
#define NCOL 66
#define BUFB (10 * NCOL * 32)      // 21120 bytes

__global__ __launch_bounds__(512, 2) void conv_mfma2(
    const float* __restrict__ x, const unsigned short* __restrict__ w2t,
    float* __restrict__ out) {
    __shared__ __align__(16) unsigned char xs[2 * BUFB];   // 42240 B

    const int tid  = threadIdx.x;
    const int lane = tid & 63;
    const int wave = tid >> 6;
    const int n    = lane & 31;
    const int kh   = lane >> 5;
    const int cohalf = wave & 1;
    const int rp     = wave >> 1;        // 0..3
    const int w0 = blockIdx.x * 64;
    const int h0 = blockIdx.y * 8;
    const int b  = blockIdx.z;

    // staging task (tid < 400): p = ci-pair(8), rl/rh -> row(10), q = col window(5)
    const bool sact = tid < 400;
    const int sp_ = tid & 7;
    const int srl = (tid >> 3) & 1;
    const int t4  = tid >> 4;            // 0..24
    const int sq  = t4 % 5;
    const int srh = t4 / 5;
    const int sr  = srh * 2 + srl;       // 0..9
    const int shh = h0 - 1 + sr;
    const bool shok = sact && (unsigned)shh < (unsigned)HH;
    const int wq = w0 - 4 + 16 * sq;     // aligned window start (multiple of 4)

    float4 La[4], Lb[4];

    f32x16 acc[2][2];
    #pragma unroll
    for (int rs = 0; rs < 2; ++rs)
        #pragma unroll
        for (int g = 0; g < 2; ++g)
            #pragma unroll
            for (int q = 0; q < 16; ++q) acc[rs][g][q] = 0.f;

    const unsigned short* w2base = w2t + (size_t)b * 9 * 4096
                                 + (size_t)(cohalf * 32 + n) * 64 + kh * 8;

    auto LOADS = [&](int cnk) {
        #pragma unroll
        for (int jj = 0; jj < 4; ++jj) {
            La[jj] = make_float4(0.f, 0.f, 0.f, 0.f);
            Lb[jj] = make_float4(0.f, 0.f, 0.f, 0.f);
        }
        if (shok) {
            const float* s0 = x + ((size_t)(b * CI + cnk * 16 + 2 * sp_) * HH + shh) * WW;
            const float* s1 = s0 + HH * WW;
            #pragma unroll
            for (int jj = 0; jj < 4; ++jj) {
                const int w = wq + 4 * jj;
                if ((unsigned)w <= 124u) {
                    La[jj] = *(const float4*)(s0 + w);
                    Lb[jj] = *(const float4*)(s1 + w);
                }
            }
        }
    };

    auto WRITE = [&](int cnk) {
        if (sact) {
            unsigned char* dbuf = xs + (cnk & 1) * BUFB;
            const float* la = (const float*)La;
            const float* lb = (const float*)Lb;
            #pragma unroll
            for (int e = 0; e < 16; ++e) {
                const int c = 16 * sq - 3 + e;
                if ((unsigned)c < (unsigned)NCOL) {
                    const unsigned v = (unsigned)f2bf(la[e]) | ((unsigned)f2bf(lb[e]) << 16);
                    *(unsigned*)(dbuf + (sr * NCOL + c) * 32 + ((4 * sp_) ^ ((c & 1) << 4))) = v;
                }
            }
        }
    };

    auto COMPUTE = [&](int cnk) {
        const unsigned char* rb = xs + (cnk & 1) * BUFB;
        const unsigned short* wb = w2base + cnk * 16;
        #pragma unroll
        for (int v = 0; v < 3; ++v) {
            const bf16x8 Af0 = *(const bf16x8*)(wb + (0 * 3 + v) * 4096);
            const bf16x8 Af1 = *(const bf16x8*)(wb + (1 * 3 + v) * 4096);
            const bf16x8 Af2 = *(const bf16x8*)(wb + (2 * 3 + v) * 4096);
            #pragma unroll
            for (int g = 0; g < 2; ++g) {
                const int cc = g * 32 + n + v;
                const int koff = (kh * 16) ^ ((cc & 1) << 4);
                const unsigned char* cb = rb + cc * 32 + koff;
                const bf16x8 B0 = *(const bf16x8*)(cb + (2 * rp + 0) * (NCOL * 32));
                const bf16x8 B1 = *(const bf16x8*)(cb + (2 * rp + 1) * (NCOL * 32));
                const bf16x8 B2 = *(const bf16x8*)(cb + (2 * rp + 2) * (NCOL * 32));
                const bf16x8 B3 = *(const bf16x8*)(cb + (2 * rp + 3) * (NCOL * 32));
                acc[0][g] = __builtin_amdgcn_mfma_f32_32x32x16_bf16(Af0, B0, acc[0][g], 0, 0, 0);
                acc[1][g] = __builtin_amdgcn_mfma_f32_32x32x16_bf16(Af0, B1, acc[1][g], 0, 0, 0);
                acc[0][g] = __builtin_amdgcn_mfma_f32_32x32x16_bf16(Af1, B1, acc[0][g], 0, 0, 0);
                acc[1][g] = __builtin_amdgcn_mfma_f32_32x32x16_bf16(Af1, B2, acc[1][g], 0, 0, 0);
                acc[0][g] = __builtin_amdgcn_mfma_f32_32x32x16_bf16(Af2, B2, acc[0][g], 0, 0, 0);
                acc[1][g] = __builtin_amdgcn_mfma_f32_32x32x16_bf16(Af2, B3, acc[1][g], 0, 0, 0);
            }
        }
    };

    // prologue: stage chunk 0
    LOADS(0);
    WRITE(0);
    __syncthreads();

    #pragma unroll 1
    for (int c = 0; c < 4; ++c) {
        if (c < 3) LOADS(c + 1);        // global loads in flight during compute
        COMPUTE(c);
        if (c < 3) WRITE(c + 1);        // lands in the other buffer
        __syncthreads();
    }

    // epilogue: C row m=(reg&3)+8*(reg>>2)+4*kh (co within half), col n
    #pragma unroll
    for (int rs = 0; rs < 2; ++rs) {
        const int h = h0 + 2 * rp + rs;
        #pragma unroll
        for (int g = 0; g < 2; ++g) {
            float* op = out + ((size_t)(b * CO + cohalf * 32) * HH + h) * WW + w0 + g * 32 + n;
            #pragma unroll
            for (int reg = 0; reg < 16; ++reg) {
                const int m = (reg & 3) + 8 * (reg >> 2) + 4 * kh;
                op[(size_t)m * (HH * WW)] = acc[rs][g][reg];
            }
        }
    }
}

// ---------------------------------------------------------------------------
extern "C" void kernel_launch(void* const* d_in, const int* in_sizes, int n_in,
                              void* d_out, int out_size, void* d_ws, size_t ws_size,
                              hipStream_t stream) {
    const float* x        = (const float*)d_in[0];
    const float* prep_w   = (const float*)d_in[1];
    const float* bn_g     = (const float*)d_in[2];
    const float* bn_b     = (const float*)d_in[3];
    const float* bn_m     = (const float*)d_in[4];
    const float* bn_v     = (const float*)d_in[5];
    const float* fc_sp_w  = (const float*)d_in[6];
    const float* fc_sp_b  = (const float*)d_in[7];
    const float* fc_ch_w  = (const float*)d_in[8];
    const float* fc_ch_b  = (const float*)d_in[9];
    const float* fc_f_w   = (const float*)d_in[10];
    const float* fc_f_b   = (const float*)d_in[11];
    const float* fc_k_w   = (const float*)d_in[12];
    const float* fc_k_b   = (const float*)d_in[13];
    const float* kernels  = (const float*)d_in[14];
    float* out = (float*)d_out;
    float* ws  = (float*)d_ws;

    float* pooled = ws + WS_POOLED;
    float* cha    = ws + WS_CHA;
    float* fa     = ws + WS_FA;
    float* ka     = ws + WS_KA;
    float* sp     = ws + WS_SP;
    unsigned short* w2t = (unsigned short*)(ws + WS_W2T);

    pool_kernel<<<NB * CI, 256, 0, stream>>>(x, pooled);
    attn2_kernel<<<1, 512, 0, stream>>>(pooled, prep_w, bn_g, bn_b, bn_m, bn_v,
                                        fc_sp_w, fc_sp_b, fc_ch_w, fc_ch_b,
                                        fc_f_w, fc_f_b, fc_k_w, fc_k_b,
                                        sp, cha, fa, ka);
    w2t_kernel<<<(NB * 9 * CO * CI) / 256, 256, 0, stream>>>(kernels, sp, cha, fa, ka, w2t);
    {
        dim3 grid(WW / 64, HH / 8, NB);
        conv_mfma2<<<grid, 512, 0, stream>>>(x, w2t, out);
    }
}